// Round 6
// baseline (2807.171 us; speedup 1.0000x reference)
//
#include <hip/hip_runtime.h>
#include <cstdint>
#include <algorithm>

// ---------------- problem constants ----------------
#define N1c 100000
#define N2c 80000
#define EPSc 1e-5f
#define STRIDE_N1 102400   // 100 blocks of 1024 (>= N1+1 bins)
#define STRIDE_N2 81920    // 80 blocks of 1024  (>= N2+1 bins)

// ---------------- CSR build: one pass for ALL k-chunks of a layer ----------
__global__ __launch_bounds__(256) void rank2d_kernel(
    const int* __restrict__ out_idx, int* __restrict__ rank,
    int* __restrict__ bins, int E, int M, int q, int stride)
{
    for (int e = blockIdx.x * 256 + threadIdx.x; e < E; e += gridDim.x * 256) {
        int chunk = (e / M) / q;
        rank[e] = atomicAdd(&bins[chunk * stride + out_idx[e]], 1);
    }
}

__global__ __launch_bounds__(256) void scan1(
    const int* __restrict__ bins, int* __restrict__ ptr,
    int* __restrict__ bsums, int n)
{
    __shared__ int lds[256];
    int base = blockIdx.x * 1024;
    int v[4]; int t = 0;
    #pragma unroll
    for (int i = 0; i < 4; ++i) {
        int idx = base + threadIdx.x * 4 + i;
        v[i] = idx < n ? bins[idx] : 0;
        t += v[i];
    }
    lds[threadIdx.x] = t; __syncthreads();
    for (int off = 1; off < 256; off <<= 1) {
        int x = threadIdx.x >= off ? lds[threadIdx.x - off] : 0;
        __syncthreads();
        lds[threadIdx.x] += x;
        __syncthreads();
    }
    int run = lds[threadIdx.x] - t;
    if (threadIdx.x == 255) bsums[blockIdx.x] = lds[255];
    #pragma unroll
    for (int i = 0; i < 4; ++i) {
        int idx = base + threadIdx.x * 4 + i;
        if (idx < n) ptr[idx] = run;
        run += v[i];
    }
}

// wave-parallel exclusive scan of block sums; one wave per chunk
__global__ __launch_bounds__(256) void scan2w(
    int* __restrict__ bsums, int bpc, int nch)
{
    int wave = threadIdx.x >> 6, lane = threadIdx.x & 63;
    for (int c = wave; c < nch; c += 4) {
        int carry = 0;
        for (int base = 0; base < bpc; base += 64) {
            int i = c * bpc + base + lane;
            bool ok = (base + lane) < bpc;
            int orig = ok ? bsums[i] : 0;
            int v = orig;
            #pragma unroll
            for (int off = 1; off < 64; off <<= 1) {
                int t = __shfl_up(v, off, 64);
                if (lane >= off) v += t;
            }
            if (ok) bsums[i] = v - orig + carry;
            carry += __shfl(v, 63, 64);
        }
    }
}

__global__ __launch_bounds__(256) void scan3(
    int* __restrict__ ptr, const int* __restrict__ bsums, int n)
{
    int idx = blockIdx.x * 1024 + threadIdx.x * 4;
    int add = bsums[blockIdx.x];
    #pragma unroll
    for (int i = 0; i < 4; ++i)
        if (idx + i < n) ptr[idx + i] += add;
}

// ---------------- conv1a special: scatter (x_val, k) 8B per edge ----------
__global__ __launch_bounds__(256) void scatter_1a(
    const float* __restrict__ x, const int* __restrict__ iin,
    const int* __restrict__ iout, const int* __restrict__ ptr,
    const int* __restrict__ rank, float2* __restrict__ payload, int E, int M)
{
    for (int e = blockIdx.x * 256 + threadIdx.x; e < E; e += gridDim.x * 256) {
        int k = e / M;
        float2 p; p.x = x[iin[e]]; p.y = __int_as_float(k);
        payload[ptr[iout[e]] + rank[e]] = p;
    }
}

// out[o][c] = relu( sum_e val_e * W[k_e][c] ), W (125x32) in LDS
__global__ __launch_bounds__(256) void phaseB_1a(
    const float2* __restrict__ payload, const int* __restrict__ ptr,
    const float* __restrict__ W, float* __restrict__ out, int n)
{
    __shared__ float Wl[125 * 32];
    for (int i = threadIdx.x; i < 125 * 32; i += 256) Wl[i] = W[i];
    __syncthreads();
    int total = n * 32;
    for (int idx = blockIdx.x * 256 + threadIdx.x; idx < total; idx += gridDim.x * 256) {
        int o = idx >> 5, c = idx & 31;
        int s0 = ptr[o], s1 = ptr[o + 1];
        float acc = 0.f;
        for (int s = s0; s < s1; ++s) {
            float2 p = payload[s];
            acc = fmaf(p.x, Wl[(__float_as_int(p.y) << 5) + c], acc);
        }
        out[idx] = fmaxf(acc, 0.f);
    }
}

// ---------------- Phase A: tiled gather-GEMM, register tiles --------------
// Thread tile = TP pairs x TC couts, TC split into TC/4 groups CTILE/2 apart
// (bank-conflict-free). CIN chunked by 32 to keep LDS small (occupancy).
// GMODE: 0 = plain gather, 2 = BN(scale/shift)+ReLU at gather.
template <int CIN, int CTILE, int WST, int TP, int TC, int GMODE>
__global__ __launch_bounds__(256) void phaseA8(
    const float* __restrict__ feats, const float* __restrict__ W,
    const int* __restrict__ in_idx, const int* __restrict__ out_idx,
    const int* __restrict__ ptr, const int* __restrict__ rank,
    float* __restrict__ contrib, int M,
    const float* __restrict__ sc, const float* __restrict__ sh)
{
    constexpr int NCG = CTILE / TC;      // cout groups
    constexpr int PPG = 256 / NCG;       // pair groups
    constexpr int PP  = PPG * TP;        // pairs per block
    constexpr int CINC = (CIN > 32) ? 32 : CIN;
    constexpr int NCH  = CIN / CINC;
    constexpr int LOADERS = 256 / PP;
    constexpr int SITER = CINC / 4 / LOADERS;
    constexpr int FTS = PP + 4;
    constexpr int NG  = TC / 4;          // cout float4-groups per thread

    const int k = blockIdx.y;
    __shared__ float Wl[CINC][CTILE];
    __shared__ float ft[CINC][FTS];
    __shared__ int sslot[PP];

    const int cg = threadIdx.x % NCG;
    const int pg = threadIdx.x / NCG;
    const int p0 = pg * TP;
    const int pl = threadIdx.x % PP;
    const int ll = threadIdx.x / PP;

    const int* iin  = in_idx  + (size_t)k * M;
    const int* iout = out_idx + (size_t)k * M;
    const int* rk   = rank    + (size_t)k * M;
    const float* Wk = W + (size_t)k * CIN * WST;

    for (int base = blockIdx.x * PP; base < M; base += gridDim.x * PP) {
        float acc[TP][TC];
        #pragma unroll
        for (int p = 0; p < TP; ++p)
            #pragma unroll
            for (int c = 0; c < TC; ++c) acc[p][c] = 0.f;

        #pragma unroll
        for (int ch = 0; ch < NCH; ++ch) {
            __syncthreads();
            // stage W chunk
            for (int i = threadIdx.x; i < CINC * (CTILE / 4); i += 256) {
                int j = i / (CTILE / 4), c4 = (i % (CTILE / 4)) * 4;
                *(float4*)&Wl[j][c4] =
                    *(const float4*)(Wk + (size_t)(ch * CINC + j) * WST + c4);
            }
            int p = base + pl;
            if (p < M) {
                if (ch == 0 && threadIdx.x < PP)
                    sslot[pl] = ptr[iout[p]] + rk[p];
                const float* fr = feats + (size_t)iin[p] * CIN + ch * CINC;
                #pragma unroll
                for (int i = 0; i < SITER; ++i) {
                    int j4 = (ll + i * LOADERS) * 4;
                    float4 v = *(const float4*)(fr + j4);
                    if (GMODE == 2) {
                        float4 s4 = *(const float4*)(sc + ch * CINC + j4);
                        float4 h4 = *(const float4*)(sh + ch * CINC + j4);
                        v.x = fmaxf(fmaf(v.x, s4.x, h4.x), 0.f);
                        v.y = fmaxf(fmaf(v.y, s4.y, h4.y), 0.f);
                        v.z = fmaxf(fmaf(v.z, s4.z, h4.z), 0.f);
                        v.w = fmaxf(fmaf(v.w, s4.w, h4.w), 0.f);
                    }
                    ft[j4 + 0][pl] = v.x;
                    ft[j4 + 1][pl] = v.y;
                    ft[j4 + 2][pl] = v.z;
                    ft[j4 + 3][pl] = v.w;
                }
            }
            __syncthreads();

            #pragma unroll 4
            for (int j = 0; j < CINC; ++j) {
                float fv[TP], wv[TC];
                #pragma unroll
                for (int g = 0; g < TP / 4; ++g)
                    *(float4*)&fv[g * 4] = *(const float4*)&ft[j][p0 + g * 4];
                #pragma unroll
                for (int g = 0; g < NG; ++g)
                    *(float4*)&wv[g * 4] =
                        *(const float4*)&Wl[j][cg * 4 + g * (CTILE / 2)];
                #pragma unroll
                for (int p = 0; p < TP; ++p)
                    #pragma unroll
                    for (int c = 0; c < TC; ++c)
                        acc[p][c] = fmaf(fv[p], wv[c], acc[p][c]);
            }
        }

        #pragma unroll
        for (int q = 0; q < TP; ++q) {
            if (base + p0 + q < M) {
                size_t s = (size_t)sslot[p0 + q];
                #pragma unroll
                for (int g = 0; g < NG; ++g) {
                    float4 o4;
                    o4.x = acc[q][g * 4 + 0]; o4.y = acc[q][g * 4 + 1];
                    o4.z = acc[q][g * 4 + 2]; o4.w = acc[q][g * 4 + 3];
                    *(float4*)&contrib[s * CTILE + cg * 4 + g * (CTILE / 2)] = o4;
                }
            }
        }
    }
}

// ---------------- Phase B: float4 segmented sum (+fused fp64 BN stats) ----
template <int CSTR, bool STATS>
__global__ __launch_bounds__(256) void phaseB4(
    const float* __restrict__ contrib, const int* __restrict__ ptr,
    float* __restrict__ out, int n, int ostr, int accum,
    double* __restrict__ statsbuf, int sqoff)
{
    constexpr int C4 = CSTR / 4;   // 256 % C4 == 0 for CSTR in {32,64,128,256}
    float4 s1 = {0, 0, 0, 0}, s2 = {0, 0, 0, 0};
    int total = n * C4;
    for (int idx = blockIdx.x * 256 + threadIdx.x; idx < total; idx += gridDim.x * 256) {
        int o = idx / C4, c = (idx % C4) * 4;
        int a = ptr[o], b = ptr[o + 1];
        float4 acc;
        if (accum) acc = *(const float4*)&out[(size_t)o * ostr + c];
        else { acc.x = acc.y = acc.z = acc.w = 0.f; }
        for (int s = a; s < b; ++s) {
            float4 v = *(const float4*)&contrib[(size_t)s * CSTR + c];
            acc.x += v.x; acc.y += v.y; acc.z += v.z; acc.w += v.w;
        }
        *(float4*)&out[(size_t)o * ostr + c] = acc;
        if (STATS) {
            s1.x += acc.x; s1.y += acc.y; s1.z += acc.z; s1.w += acc.w;
            s2.x += acc.x * acc.x; s2.y += acc.y * acc.y;
            s2.z += acc.z * acc.z; s2.w += acc.w * acc.w;
        }
    }
    if constexpr (STATS) {
        __shared__ double l1[256][4], l2[256][4];
        l1[threadIdx.x][0] = s1.x; l1[threadIdx.x][1] = s1.y;
        l1[threadIdx.x][2] = s1.z; l1[threadIdx.x][3] = s1.w;
        l2[threadIdx.x][0] = s2.x; l2[threadIdx.x][1] = s2.y;
        l2[threadIdx.x][2] = s2.z; l2[threadIdx.x][3] = s2.w;
        __syncthreads();
        for (int off = 128; off >= C4; off >>= 1) {
            if (threadIdx.x < (unsigned)off) {
                #pragma unroll
                for (int i = 0; i < 4; ++i) {
                    l1[threadIdx.x][i] += l1[threadIdx.x + off][i];
                    l2[threadIdx.x][i] += l2[threadIdx.x + off][i];
                }
            }
            __syncthreads();
        }
        if (threadIdx.x < C4) {
            #pragma unroll
            for (int i = 0; i < 4; ++i) {
                atomicAdd(&statsbuf[threadIdx.x * 4 + i], l1[threadIdx.x][i]);
                atomicAdd(&statsbuf[sqoff + threadIdx.x * 4 + i], l2[threadIdx.x][i]);
            }
        }
    }
}

// ---------------- BN helpers (fp64 stats) ----------------
template <int C>
__global__ __launch_bounds__(256) void make_scsh(
    const double* __restrict__ sums, const float* __restrict__ g,
    const float* __restrict__ b, float* __restrict__ sc, float* __restrict__ sh,
    double inv_n)
{
    int c = threadIdx.x;
    if (c < C) {
        double mean = sums[c] * inv_n;
        double var  = sums[C + c] * inv_n - mean * mean;
        float s = g[c] * (float)(1.0 / sqrt(var + (double)EPSc));
        sc[c] = s;
        sh[c] = b[c] - (float)mean * s;
    }
}

template <int C>
__global__ __launch_bounds__(256) void bn_apply_relu4(
    float* __restrict__ x, int n, const double* __restrict__ sums,
    const float* __restrict__ g, const float* __restrict__ b)
{
    constexpr int C4 = C / 4;
    const int c = (threadIdx.x % C4) * 4;
    const double inv_n = 1.0 / (double)n;
    float scale[4], shift[4];
    #pragma unroll
    for (int i = 0; i < 4; ++i) {
        double mean = sums[c + i] * inv_n;
        double var  = sums[C + c + i] * inv_n - mean * mean;
        scale[i] = g[c + i] * (float)(1.0 / sqrt(var + (double)EPSc));
        shift[i] = b[c + i] - (float)mean * scale[i];
    }
    size_t total = (size_t)n * C4;
    size_t stride = (size_t)gridDim.x * 256;
    for (size_t t = (size_t)blockIdx.x * 256 + threadIdx.x; t < total; t += stride) {
        size_t o = t / C4;
        float4 v = *(const float4*)&x[(o * C4 + t % C4) * 4];
        v.x = fmaxf(fmaf(v.x, scale[0], shift[0]), 0.f);
        v.y = fmaxf(fmaf(v.y, scale[1], shift[1]), 0.f);
        v.z = fmaxf(fmaf(v.z, scale[2], shift[2]), 0.f);
        v.w = fmaxf(fmaf(v.w, scale[3], shift[3]), 0.f);
        *(float4*)&x[(o * C4 + t % C4) * 4] = v;
    }
}

// ---------------- host-side helpers ----------------
struct Plan { int q, nch; };

static Plan make_plan(long long tot_elems, int K, long long cap, int maxch)
{
    if (cap < 1) cap = 1;
    long long nch0 = (tot_elems + cap - 1) / cap;
    if (nch0 < 1) nch0 = 1;
    if (nch0 > K) nch0 = K;
    int q = (int)((K + nch0 - 1) / nch0);
    int nch = (K + q - 1) / q;
    if (nch > maxch) { q = (K + maxch - 1) / maxch; nch = (K + q - 1) / q; }
    return { q, nch };
}

static void build_csr2d(const int* iout, int* rank, int* bins, int* ptr, int* bsums,
                        int E, int M, int q, int nch, int stride, hipStream_t s)
{
    hipMemsetAsync(bins, 0, (size_t)nch * stride * sizeof(int), s);
    int gb = std::min(2048, (E + 255) / 256);
    hipLaunchKernelGGL(rank2d_kernel, dim3(gb), dim3(256), 0, s, iout, rank, bins, E, M, q, stride);
    int totalbins = nch * stride, nb = totalbins / 1024, bpc = stride / 1024;
    hipLaunchKernelGGL(scan1, dim3(nb), dim3(256), 0, s, bins, ptr, bsums, totalbins);
    hipLaunchKernelGGL(scan2w, dim3(1), dim3(256), 0, s, bsums, bpc, nch);
    hipLaunchKernelGGL(scan3, dim3(nb), dim3(256), 0, s, ptr, bsums, totalbins);
}

// One full layer (no cout split): k-chunked as needed.
template <int CIN, int COUT, int TP, int TC, int GMODE, bool STATS>
static void run_layer(const float* feats, const float* W,
                      const int* iin, const int* iout, float* outp,
                      int M, int K, int n_out, int stride, int maxch,
                      int* bins, int* ptr, int* bsums, int* rank, float* contrib,
                      long long cap, const float* sc, const float* sh,
                      double* statsbuf, hipStream_t s)
{
    constexpr int NCG = COUT / TC;
    constexpr int PP  = (256 / NCG) * TP;
    Plan pl = make_plan((long long)K * M * COUT, K, cap, maxch);
    build_csr2d(iout, rank, bins, ptr, bsums, K * M, M, pl.q, pl.nch, stride, s);
    for (int ch = 0; ch < pl.nch; ++ch) {
        int k0 = ch * pl.q;
        int qc = std::min(pl.q, K - k0);
        dim3 g((M + PP - 1) / PP, qc);
        hipLaunchKernelGGL((phaseA8<CIN, COUT, COUT, TP, TC, GMODE>), g, dim3(256), 0, s,
                           feats, W + (size_t)k0 * CIN * COUT,
                           iin + (size_t)k0 * M, iout + (size_t)k0 * M,
                           ptr + (size_t)ch * stride, rank + (size_t)k0 * M,
                           contrib, M, sc, sh);
        bool last = (ch == pl.nch - 1);
        if (STATS && last)
            hipLaunchKernelGGL((phaseB4<COUT, true>), dim3(2048), dim3(256), 0, s,
                               contrib, ptr + (size_t)ch * stride, outp, n_out, COUT,
                               ch ? 1 : 0, statsbuf, COUT);
        else
            hipLaunchKernelGGL((phaseB4<COUT, false>), dim3(2048), dim3(256), 0, s,
                               contrib, ptr + (size_t)ch * stride, outp, n_out, COUT,
                               ch ? 1 : 0, (double*)nullptr, 0);
    }
}

extern "C" void kernel_launch(void* const* d_in, const int* in_sizes, int n_in,
                              void* d_out, int out_size, void* d_ws, size_t ws_size,
                              hipStream_t stream)
{
    const float* x_feats = (const float*)d_in[0];
    const float* w1a = (const float*)d_in[1];
    const float* w1b = (const float*)d_in[2];
    const float* w1c = (const float*)d_in[3];
    const float* w2  = (const float*)d_in[4];
    const float* w3a = (const float*)d_in[5];
    const float* w3b = (const float*)d_in[6];
    const float* bn1b_g = (const float*)d_in[7];
    const float* bn1b_b = (const float*)d_in[8];
    const float* bn1c_g = (const float*)d_in[9];
    const float* bn1c_b = (const float*)d_in[10];
    const float* bn3a_g = (const float*)d_in[11];
    const float* bn3a_b = (const float*)d_in[12];
    const float* bn3b_g = (const float*)d_in[13];
    const float* bn3b_b = (const float*)d_in[14];
    const int* km1a_in  = (const int*)d_in[15];
    const int* km1a_out = (const int*)d_in[16];
    const int* km1b_in  = (const int*)d_in[17];
    const int* km1b_out = (const int*)d_in[18];
    const int* km1c_in  = (const int*)d_in[19];
    const int* km1c_out = (const int*)d_in[20];
    const int* km2_in   = (const int*)d_in[21];
    const int* km2_out  = (const int*)d_in[22];
    const int* km3a_in  = (const int*)d_in[23];
    const int* km3a_out = (const int*)d_in[24];
    const int* km3b_in  = (const int*)d_in[25];
    const int* km3b_out = (const int*)d_in[26];

    float* out  = (float*)d_out;
    float* x_e1 = out;                       // [N1,32]
    float* x_e2 = out + (size_t)N1c * 32;    // [N2,256]

    // ---- workspace layout (float-element offsets, 16B-aligned) ----
    float* ws = (float*)d_ws;
    float*  poolA  = ws;                        // 10,240,000 (h1 -> h3)
    float*  poolB  = poolA + 10240000;          //  5,120,000 (h2 -> h2b)
    double* dstats = (double*)(poolB + 5120000);//  2,048 doubles
    float*  scsh   = (float*)(dstats + 2048);   //  1,024
    int*    bins   = (int*)(scsh + 1024);       //  819,200
    int*    ptr    = bins + 819200;             //  819,200
    int*    bsums  = ptr + 819200;              //  1,024
    int*    rank   = bsums + 1024;              //  2,500,000
    float*  contrib = (float*)(rank + 2500000);
    const long long FIXED = 10240000LL + 5120000 + 4096 + 1024
                          + 819200 + 819200 + 1024 + 2500000;
    long long cap = (long long)(ws_size / 4) - FIXED - 32;
    if (cap < 1) cap = 1;

    float* h1  = poolA;   // [N1,32]
    float* h3  = poolA;   // [N2,128] (h1 dead by then)
    float* h2  = poolB;   // [N1,32]
    float* h2b = poolB;   // [N2,64]  (h2 dead by then)

    double* dst1b = dstats;
    double* dst1c = dstats + 512;
    double* dst3a = dstats + 1024;
    double* dst3b = dstats + 1536;
    float* sc1b = scsh,       *sh1b = scsh + 32;
    float* sc3a = scsh + 256, *sh3a = scsh + 384;

    hipMemsetAsync(dstats, 0, 2048 * sizeof(double), stream);

    // ---- conv1a (1->32, K=125) + ReLU: scatter (val,k) + W-in-LDS reduce ----
    {
        build_csr2d(km1a_out, rank, bins, ptr, bsums, 125 * 20000, 20000, 125, 1,
                    STRIDE_N1, stream);
        hipLaunchKernelGGL(scatter_1a, dim3(2048), dim3(256), 0, stream,
                           x_feats, km1a_in, km1a_out, ptr, rank, (float2*)contrib,
                           125 * 20000, 20000);
        hipLaunchKernelGGL(phaseB_1a, dim3(2048), dim3(256), 0, stream,
                           (const float2*)contrib, ptr, w1a, h1, N1c);
    }

    // ---- conv1b (32->32, K=125): raw out + fp64 stats; BN fused at next gather
    run_layer<32, 32, 4, 4, 0, true>(h1, w1b, km1b_in, km1b_out, h2, 20000, 125, N1c,
                                     STRIDE_N1, 8, bins, ptr, bsums, rank, contrib,
                                     cap, nullptr, nullptr, dst1b, stream);
    hipLaunchKernelGGL((make_scsh<32>), dim3(1), dim3(256), 0, stream,
                       dst1b, bn1b_g, bn1b_b, sc1b, sh1b, 1.0 / N1c);

    // ---- conv1c (32->32, K=125): BN(h2)+ReLU fused at gather; x_e1 raw + stats
    run_layer<32, 32, 4, 4, 2, true>(h2, w1c, km1c_in, km1c_out, x_e1, 20000, 125, N1c,
                                     STRIDE_N1, 8, bins, ptr, bsums, rank, contrib,
                                     cap, sc1b, sh1b, dst1c, stream);
    hipLaunchKernelGGL((bn_apply_relu4<32>), dim3(2048), dim3(256), 0, stream,
                       x_e1, N1c, dst1c, bn1c_g, bn1c_b);

    // ---- conv2 (32->64, K=27): plain, no activation ----
    run_layer<32, 64, 4, 8, 0, false>(x_e1, w2, km2_in, km2_out, h2b, 30000, 27, N2c,
                                      STRIDE_N2, 10, bins, ptr, bsums, rank, contrib,
                                      cap, nullptr, nullptr, nullptr, stream);

    // ---- conv3a (64->128, K=27): raw out + stats; BN fused at conv3b gather
    run_layer<64, 128, 8, 8, 0, true>(h2b, w3a, km3a_in, km3a_out, h3, 20000, 27, N2c,
                                      STRIDE_N2, 10, bins, ptr, bsums, rank, contrib,
                                      cap, nullptr, nullptr, dst3a, stream);
    hipLaunchKernelGGL((make_scsh<128>), dim3(1), dim3(256), 0, stream,
                       dst3a, bn3a_g, bn3a_b, sc3a, sh3a, 1.0 / N2c);

    // ---- conv3b (128->256, K=27): cout-split into two 128-halves ----
    {
        const int M = 20000, K = 27;
        Plan pl = make_plan((long long)K * M * 128, K, cap, 10);
        build_csr2d(km3b_out, rank, bins, ptr, bsums, K * M, M, pl.q, pl.nch,
                    STRIDE_N2, stream);
        constexpr int PP = (256 / (128 / 8)) * 8;   // 128 pairs per block
        for (int half = 0; half < 2; ++half) {
            for (int ch = 0; ch < pl.nch; ++ch) {
                int k0 = ch * pl.q;
                int qc = std::min(pl.q, K - k0);
                dim3 g((M + PP - 1) / PP, qc);
                hipLaunchKernelGGL((phaseA8<128, 128, 256, 8, 8, 2>), g, dim3(256), 0, stream,
                                   h3, w3b + half * 128 + (size_t)k0 * 128 * 256,
                                   km3b_in + (size_t)k0 * M, km3b_out + (size_t)k0 * M,
                                   ptr + (size_t)ch * STRIDE_N2, rank + (size_t)k0 * M,
                                   contrib, M, sc3a, sh3a);
                bool last = (ch == pl.nch - 1);
                if (last)
                    hipLaunchKernelGGL((phaseB4<128, true>), dim3(2048), dim3(256), 0, stream,
                                       contrib, ptr + (size_t)ch * STRIDE_N2,
                                       x_e2 + half * 128, N2c, 256, ch ? 1 : 0,
                                       dst3b + half * 128, 256);
                else
                    hipLaunchKernelGGL((phaseB4<128, false>), dim3(2048), dim3(256), 0, stream,
                                       contrib, ptr + (size_t)ch * STRIDE_N2,
                                       x_e2 + half * 128, N2c, 256, ch ? 1 : 0,
                                       (double*)nullptr, 0);
            }
        }
        hipLaunchKernelGGL((bn_apply_relu4<256>), dim3(2048), dim3(256), 0, stream,
                           x_e2, N2c, dst3b, bn3b_g, bn3b_b);
    }
}